// Round 1
// baseline (858.147 us; speedup 1.0000x reference)
//
#include <hip/hip_runtime.h>

#define D 64

// Phase 1: agg[dst] += x[src]  (one wave per edge group: 64 lanes = 64 floats/row)
__global__ void scatter_kernel(const float* __restrict__ x,
                               const int* __restrict__ src,
                               const int* __restrict__ dst,
                               float* __restrict__ agg,
                               int n_edges) {
    int e = blockIdx.x * (blockDim.x >> 6) + (threadIdx.x >> 6);
    int lane = threadIdx.x & 63;
    if (e >= n_edges) return;
    // src[e]/dst[e] are wave-uniform; same-address load broadcasts.
    int s = src[e];
    int d = dst[e];
    float v = x[(size_t)s * D + lane];
    unsafeAtomicAdd(&agg[(size_t)d * D + lane], v);
}

// Phase 2: x_out[n] = x_in[n] @ W_self + agg[n] @ W_msg + b   (+ ReLU)
// One wave per node; lane j owns output column j. W matrices staged in LDS;
// x/agg row values broadcast across the wave via shuffles.
__global__ void dense_kernel(const float* __restrict__ xin,
                             const float* __restrict__ agg,
                             const float* __restrict__ Wself,
                             const float* __restrict__ Wmsg,
                             const float* __restrict__ bias,
                             float* __restrict__ xout,
                             int n_nodes, int do_relu) {
    __shared__ float Ws[D * D];
    __shared__ float Wm[D * D];
    for (int i = threadIdx.x; i < D * D; i += blockDim.x) {
        Ws[i] = Wself[i];
        Wm[i] = Wmsg[i];
    }
    __syncthreads();

    int lane = threadIdx.x & 63;
    int wave = threadIdx.x >> 6;
    int wpb = blockDim.x >> 6;
    float bj = bias[lane];

    for (int n = blockIdx.x * wpb + wave; n < n_nodes; n += gridDim.x * wpb) {
        float xv = xin[(size_t)n * D + lane];
        float av = agg[(size_t)n * D + lane];
        float acc = bj;
#pragma unroll
        for (int k = 0; k < D; ++k) {
            float xs = __shfl(xv, k, 64);
            float as = __shfl(av, k, 64);
            // LDS: addr (k*64+lane)*4 -> bank lane%32 -> 2-way aliasing (free on CDNA4)
            acc += xs * Ws[k * D + lane] + as * Wm[k * D + lane];
        }
        if (do_relu) acc = fmaxf(acc, 0.f);
        xout[(size_t)n * D + lane] = acc;
    }
}

extern "C" void kernel_launch(void* const* d_in, const int* in_sizes, int n_in,
                              void* d_out, int out_size, void* d_ws, size_t ws_size,
                              hipStream_t stream) {
    const float* x0    = (const float*)d_in[0];
    const int*   ei    = (const int*)d_in[1];
    const float* Wmsg  = (const float*)d_in[2];
    const float* Wself = (const float*)d_in[3];
    const float* bias  = (const float*)d_in[4];
    float* out = (float*)d_out;

    const int N = in_sizes[0] / D;      // 50000
    const int E = in_sizes[1] / 2;      // 800000
    const int n_layers = in_sizes[4] / D;  // 3

    const int* src = ei;
    const int* dst = ei + E;

    float* agg = (float*)d_ws;          // N*D floats = 12.8 MB
    const size_t agg_bytes = (size_t)N * D * sizeof(float);

    const int EPB = 256 / 64;           // 4 edges per 256-thread block
    const int scatter_blocks = (E + EPB - 1) / EPB;

    for (int layer = 0; layer < n_layers; ++layer) {
        hipMemsetAsync(agg, 0, agg_bytes, stream);
        const float* xin = (layer == 0) ? x0 : out;
        scatter_kernel<<<scatter_blocks, 256, 0, stream>>>(xin, src, dst, agg, E);
        dense_kernel<<<1024, 256, 0, stream>>>(
            xin, agg,
            Wself + (size_t)layer * D * D,
            Wmsg  + (size_t)layer * D * D,
            bias  + (size_t)layer * D,
            out, N, (layer < n_layers - 1) ? 1 : 0);
    }
}

// Round 2
// 670.107 us; speedup vs baseline: 1.2806x; 1.2806x over previous
//
#include <hip/hip_runtime.h>

#define D 64

// ================= CSR build (counting sort by dst), once per call ==========
__global__ void hist_kernel(const int* __restrict__ dst, int* __restrict__ deg, int E) {
    int e = blockIdx.x * blockDim.x + threadIdx.x;
    if (e < E) atomicAdd(&deg[dst[e]], 1);
}

// Single-block exclusive scan over n degrees -> row_ptr[n+1], cursor copy.
__global__ void scan_kernel(const int* __restrict__ deg, int* __restrict__ row_ptr,
                            int* __restrict__ cursor, int n) {
    __shared__ int part[1024];
    int t = threadIdx.x;
    int chunk = (n + 1023) >> 10;
    int beg = t * chunk;
    int end = min(beg + chunk, n);
    int s = 0;
    for (int i = beg; i < end; ++i) s += deg[i];
    part[t] = s;
    __syncthreads();
    // inclusive scan of 1024 partials
    for (int off = 1; off < 1024; off <<= 1) {
        int v = (t >= off) ? part[t - off] : 0;
        __syncthreads();
        part[t] += v;
        __syncthreads();
    }
    int run = (t == 0) ? 0 : part[t - 1];
    for (int i = beg; i < end; ++i) {
        row_ptr[i] = run;
        cursor[i] = run;
        run += deg[i];
    }
    if (t == 1023) row_ptr[n] = run;   // t=1023 holds the grand total
}

__global__ void perm_kernel(const int* __restrict__ src, const int* __restrict__ dst,
                            int* __restrict__ cursor, int* __restrict__ sorted_src, int E) {
    int e = blockIdx.x * blockDim.x + threadIdx.x;
    if (e < E) {
        int p = atomicAdd(&cursor[dst[e]], 1);
        sorted_src[p] = src[e];
    }
}

// ============ fused layer: gather-reduce + dense, one wave per node =========
// out[n] = xin[n]@Wself + (sum_{e in CSR row n} xin[src_e])@Wmsg + b  (+ReLU)
__global__ void fused_layer(const float* __restrict__ xin,
                            const int* __restrict__ row_ptr,
                            const int* __restrict__ sorted_src,
                            const float* __restrict__ Wself,
                            const float* __restrict__ Wmsg,
                            const float* __restrict__ bias,
                            float* __restrict__ xout,
                            int n_nodes, int do_relu) {
    __shared__ float Ws[D * D];
    __shared__ float Wm[D * D];
    for (int i = threadIdx.x; i < D * D; i += blockDim.x) {
        Ws[i] = Wself[i];
        Wm[i] = Wmsg[i];
    }
    __syncthreads();

    int lane = threadIdx.x & 63;
    int wave = threadIdx.x >> 6;
    int n = blockIdx.x * (blockDim.x >> 6) + wave;
    if (n >= n_nodes) return;

    int beg = row_ptr[n];      // wave-uniform scalar loads
    int end = row_ptr[n + 1];

    float a = 0.f;
    int e = beg;
    for (; e + 4 <= end; e += 4) {          // 4 independent gathers in flight
        int s0 = sorted_src[e + 0];
        int s1 = sorted_src[e + 1];
        int s2 = sorted_src[e + 2];
        int s3 = sorted_src[e + 3];
        float v0 = xin[(size_t)s0 * D + lane];
        float v1 = xin[(size_t)s1 * D + lane];
        float v2 = xin[(size_t)s2 * D + lane];
        float v3 = xin[(size_t)s3 * D + lane];
        a += (v0 + v1) + (v2 + v3);
    }
    for (; e < end; ++e) a += xin[(size_t)sorted_src[e] * D + lane];

    float xv = xin[(size_t)n * D + lane];
    float acc = bias[lane];
#pragma unroll
    for (int k = 0; k < D; ++k) {
        // 2-way LDS bank aliasing only (free on CDNA4)
        acc += __shfl(xv, k, 64) * Ws[k * D + lane]
             + __shfl(a,  k, 64) * Wm[k * D + lane];
    }
    if (do_relu) acc = fmaxf(acc, 0.f);
    xout[(size_t)n * D + lane] = acc;
}

// ================= round-1 fallback (atomic scatter) ========================
__global__ void scatter_kernel(const float* __restrict__ x,
                               const int* __restrict__ src,
                               const int* __restrict__ dst,
                               float* __restrict__ agg,
                               int n_edges) {
    int e = blockIdx.x * (blockDim.x >> 6) + (threadIdx.x >> 6);
    int lane = threadIdx.x & 63;
    if (e >= n_edges) return;
    int s = src[e];
    int d = dst[e];
    float v = x[(size_t)s * D + lane];
    unsafeAtomicAdd(&agg[(size_t)d * D + lane], v);
}

__global__ void dense_kernel(const float* __restrict__ xin,
                             const float* __restrict__ agg,
                             const float* __restrict__ Wself,
                             const float* __restrict__ Wmsg,
                             const float* __restrict__ bias,
                             float* __restrict__ xout,
                             int n_nodes, int do_relu) {
    __shared__ float Ws[D * D];
    __shared__ float Wm[D * D];
    for (int i = threadIdx.x; i < D * D; i += blockDim.x) {
        Ws[i] = Wself[i];
        Wm[i] = Wmsg[i];
    }
    __syncthreads();
    int lane = threadIdx.x & 63;
    int wave = threadIdx.x >> 6;
    int wpb = blockDim.x >> 6;
    float bj = bias[lane];
    for (int n = blockIdx.x * wpb + wave; n < n_nodes; n += gridDim.x * wpb) {
        float xv = xin[(size_t)n * D + lane];
        float av = agg[(size_t)n * D + lane];
        float acc = bj;
#pragma unroll
        for (int k = 0; k < D; ++k) {
            acc += __shfl(xv, k, 64) * Ws[k * D + lane]
                 + __shfl(av, k, 64) * Wm[k * D + lane];
        }
        if (do_relu) acc = fmaxf(acc, 0.f);
        xout[(size_t)n * D + lane] = acc;
    }
}

// ============================================================================
extern "C" void kernel_launch(void* const* d_in, const int* in_sizes, int n_in,
                              void* d_out, int out_size, void* d_ws, size_t ws_size,
                              hipStream_t stream) {
    const float* x0    = (const float*)d_in[0];
    const int*   ei    = (const int*)d_in[1];
    const float* Wmsg  = (const float*)d_in[2];
    const float* Wself = (const float*)d_in[3];
    const float* bias  = (const float*)d_in[4];
    float* out = (float*)d_out;

    const int N = in_sizes[0] / D;         // 50000
    const int E = in_sizes[1] / 2;         // 800000
    const int n_layers = in_sizes[4] / D;  // 3

    const int* src = ei;
    const int* dst = ei + E;

    const size_t NB = (size_t)N * D * sizeof(float);                 // 12.8 MB
    const size_t need = NB + (size_t)E * 4 + (size_t)(N + 1) * 4
                      + (size_t)N * 4 + (size_t)N * 4;               // ~16.8 MB

    if (ws_size >= need) {
        // ---------------- fast path: CSR + fused gather/dense ----------------
        char* p = (char*)d_ws;
        float* A         = (float*)p;  p += NB;
        int*   sorted_src= (int*)p;    p += (size_t)E * 4;
        int*   row_ptr   = (int*)p;    p += (size_t)(N + 1) * 4;
        int*   cursor    = (int*)p;    p += (size_t)N * 4;
        int*   deg       = (int*)p;

        hipMemsetAsync(deg, 0, (size_t)N * 4, stream);
        hist_kernel<<<(E + 255) / 256, 256, 0, stream>>>(dst, deg, E);
        scan_kernel<<<1, 1024, 0, stream>>>(deg, row_ptr, cursor, N);
        perm_kernel<<<(E + 255) / 256, 256, 0, stream>>>(src, dst, cursor, sorted_src, E);

        const int WPB = 4;                       // waves per block
        const int blocks = (N + WPB - 1) / WPB;

        // ping-pong so last layer lands on d_out; reads and writes never alias
        // n_layers=3: targets are out, A, out
        const float* cur = x0;
        for (int layer = 0; layer < n_layers; ++layer) {
            int rem = n_layers - 1 - layer;            // layers after this one
            float* tgt = (rem % 2 == 0) ? out : A;
            fused_layer<<<blocks, WPB * 64, 0, stream>>>(
                cur, row_ptr, sorted_src,
                Wself + (size_t)layer * D * D,
                Wmsg  + (size_t)layer * D * D,
                bias  + (size_t)layer * D,
                tgt, N, (layer < n_layers - 1) ? 1 : 0);
            cur = tgt;
        }
    } else {
        // ---------------- fallback: round-1 atomic path ----------------------
        float* agg = (float*)d_ws;
        const int EPB = 256 / 64;
        const int scatter_blocks = (E + EPB - 1) / EPB;
        for (int layer = 0; layer < n_layers; ++layer) {
            hipMemsetAsync(agg, 0, NB, stream);
            const float* xin = (layer == 0) ? x0 : out;
            scatter_kernel<<<scatter_blocks, 256, 0, stream>>>(xin, src, dst, agg, E);
            dense_kernel<<<1024, 256, 0, stream>>>(
                xin, agg,
                Wself + (size_t)layer * D * D,
                Wmsg  + (size_t)layer * D * D,
                bias  + (size_t)layer * D,
                out, N, (layer < n_layers - 1) ? 1 : 0);
        }
    }
}

// Round 3
// 389.540 us; speedup vs baseline: 2.2030x; 1.7203x over previous
//
#include <hip/hip_runtime.h>

#define D 64

__device__ __forceinline__ float bcast(float v, int lane_lit) {
    // wave-wide broadcast via v_readlane (VALU) — avoids ds_bpermute (LDS pipe)
    return __int_as_float(__builtin_amdgcn_readlane(__float_as_int(v), lane_lit));
}

// ================= CSR build (counting sort by dst) =========================
__global__ void hist_kernel(const int* __restrict__ dst, int* __restrict__ deg, int E) {
    int i = blockIdx.x * blockDim.x + threadIdx.x;
    int E4 = E >> 2;
    if (i < E4) {
        int4 d4 = reinterpret_cast<const int4*>(dst)[i];
        atomicAdd(&deg[d4.x], 1);
        atomicAdd(&deg[d4.y], 1);
        atomicAdd(&deg[d4.z], 1);
        atomicAdd(&deg[d4.w], 1);
    }
    // tail
    int t = E4 * 4 + i;
    if (i < (E & 3)) atomicAdd(&deg[dst[E4 * 4 + i]], 1);
    (void)t;
}

// --- hierarchical exclusive scan: K1 block sums, K2 scan sums, K3 write -----
__global__ void scan_k1(const int* __restrict__ deg, int* __restrict__ bsum, int n) {
    __shared__ int sh[256];
    int t = threadIdx.x;
    int g = blockIdx.x * 256 + t;
    int v = (g < n) ? deg[g] : 0;
    sh[t] = v;
    __syncthreads();
    for (int off = 1; off < 256; off <<= 1) {
        int u = (t >= off) ? sh[t - off] : 0;
        __syncthreads();
        sh[t] += u;
        __syncthreads();
    }
    if (t == 255) bsum[blockIdx.x] = sh[255];
}

__global__ void scan_k2(const int* __restrict__ bsum, int* __restrict__ boff, int nb) {
    __shared__ int sh[1024];
    int t = threadIdx.x;
    int v = (t < nb) ? bsum[t] : 0;
    sh[t] = v;
    __syncthreads();
    for (int off = 1; off < 1024; off <<= 1) {
        int u = (t >= off) ? sh[t - off] : 0;
        __syncthreads();
        sh[t] += u;
        __syncthreads();
    }
    if (t < nb) boff[t] = sh[t] - v;   // exclusive
}

__global__ void scan_k3(const int* __restrict__ deg, const int* __restrict__ boff,
                        int* __restrict__ row_ptr, int* __restrict__ cursor, int n) {
    __shared__ int sh[256];
    int t = threadIdx.x;
    int g = blockIdx.x * 256 + t;
    int v = (g < n) ? deg[g] : 0;
    sh[t] = v;
    __syncthreads();
    for (int off = 1; off < 256; off <<= 1) {
        int u = (t >= off) ? sh[t - off] : 0;
        __syncthreads();
        sh[t] += u;
        __syncthreads();
    }
    if (g < n) {
        int excl = sh[t] - v + boff[blockIdx.x];
        row_ptr[g] = excl;
        cursor[g] = excl;
        if (g == n - 1) row_ptr[n] = excl + v;
    }
}

__global__ void perm_kernel(const int* __restrict__ src, const int* __restrict__ dst,
                            int* __restrict__ cursor, int* __restrict__ sorted_src, int E) {
    int i = blockIdx.x * blockDim.x + threadIdx.x;
    int E4 = E >> 2;
    if (i < E4) {
        int4 d4 = reinterpret_cast<const int4*>(dst)[i];
        int4 s4 = reinterpret_cast<const int4*>(src)[i];
        int p0 = atomicAdd(&cursor[d4.x], 1);
        int p1 = atomicAdd(&cursor[d4.y], 1);
        int p2 = atomicAdd(&cursor[d4.z], 1);
        int p3 = atomicAdd(&cursor[d4.w], 1);
        sorted_src[p0] = s4.x;
        sorted_src[p1] = s4.y;
        sorted_src[p2] = s4.z;
        sorted_src[p3] = s4.w;
    }
    if (i < (E & 3)) {
        int e = E4 * 4 + i;
        int p = atomicAdd(&cursor[dst[e]], 1);
        sorted_src[p] = src[e];
    }
}

// ============ fused layer v2: reg-cached W columns, readlane broadcasts =====
// out[n] = xin[n]@Wself + (sum_{e in row n} xin[src_e])@Wmsg + b  (+ReLU)
// No LDS at all: lane j holds column j of Ws/Wm in VGPRs; broadcasts via
// v_readlane (VALU pipe) with literal lane index (full unroll).
__global__ void __launch_bounds__(256)
fused_layer(const float* __restrict__ xin,
            const int* __restrict__ row_ptr,
            const int* __restrict__ sorted_src,
            const float* __restrict__ Wself,
            const float* __restrict__ Wmsg,
            const float* __restrict__ bias,
            float* __restrict__ xout,
            int n_nodes, int do_relu) {
    int lane = threadIdx.x & 63;
    int wave = threadIdx.x >> 6;
    int wpb = blockDim.x >> 6;

    // register-cache column `lane` of both weight matrices (coalesced per k)
    float Wsc[D], Wmc[D];
#pragma unroll
    for (int k = 0; k < D; ++k) {
        Wsc[k] = Wself[k * D + lane];
        Wmc[k] = Wmsg[k * D + lane];
    }
    float bj = bias[lane];

    for (int n = blockIdx.x * wpb + wave; n < n_nodes; n += gridDim.x * wpb) {
        int beg = row_ptr[n];
        int end = row_ptr[n + 1];

        // gather-reduce: a[lane] = sum of xin[src][lane], 8 loads in flight
        float a = 0.f;
        int e = beg;
        for (; e + 8 <= end; e += 8) {
            int s0 = sorted_src[e + 0], s1 = sorted_src[e + 1];
            int s2 = sorted_src[e + 2], s3 = sorted_src[e + 3];
            int s4 = sorted_src[e + 4], s5 = sorted_src[e + 5];
            int s6 = sorted_src[e + 6], s7 = sorted_src[e + 7];
            float v0 = xin[(size_t)s0 * D + lane];
            float v1 = xin[(size_t)s1 * D + lane];
            float v2 = xin[(size_t)s2 * D + lane];
            float v3 = xin[(size_t)s3 * D + lane];
            float v4 = xin[(size_t)s4 * D + lane];
            float v5 = xin[(size_t)s5 * D + lane];
            float v6 = xin[(size_t)s6 * D + lane];
            float v7 = xin[(size_t)s7 * D + lane];
            a += ((v0 + v1) + (v2 + v3)) + ((v4 + v5) + (v6 + v7));
        }
        for (; e < end; ++e) a += xin[(size_t)sorted_src[e] * D + lane];

        float xv = xin[(size_t)n * D + lane];

        // dense: 4 parallel acc chains to keep FMA latency off the critical path
        float acc0 = bj, acc1 = 0.f, acc2 = 0.f, acc3 = 0.f;
#pragma unroll
        for (int k = 0; k < D; k += 4) {
            acc0 = fmaf(bcast(xv, k + 0), Wsc[k + 0], acc0);
            acc1 = fmaf(bcast(xv, k + 1), Wsc[k + 1], acc1);
            acc2 = fmaf(bcast(xv, k + 2), Wsc[k + 2], acc2);
            acc3 = fmaf(bcast(xv, k + 3), Wsc[k + 3], acc3);
            acc0 = fmaf(bcast(a, k + 0), Wmc[k + 0], acc0);
            acc1 = fmaf(bcast(a, k + 1), Wmc[k + 1], acc1);
            acc2 = fmaf(bcast(a, k + 2), Wmc[k + 2], acc2);
            acc3 = fmaf(bcast(a, k + 3), Wmc[k + 3], acc3);
        }
        float acc = (acc0 + acc1) + (acc2 + acc3);
        if (do_relu) acc = fmaxf(acc, 0.f);
        xout[(size_t)n * D + lane] = acc;
    }
}

// ================= fallback (round-1 atomic path) ===========================
__global__ void scatter_kernel(const float* __restrict__ x,
                               const int* __restrict__ src,
                               const int* __restrict__ dst,
                               float* __restrict__ agg,
                               int n_edges) {
    int e = blockIdx.x * (blockDim.x >> 6) + (threadIdx.x >> 6);
    int lane = threadIdx.x & 63;
    if (e >= n_edges) return;
    int s = src[e];
    int d = dst[e];
    float v = x[(size_t)s * D + lane];
    unsafeAtomicAdd(&agg[(size_t)d * D + lane], v);
}

__global__ void dense_kernel(const float* __restrict__ xin,
                             const float* __restrict__ agg,
                             const float* __restrict__ Wself,
                             const float* __restrict__ Wmsg,
                             const float* __restrict__ bias,
                             float* __restrict__ xout,
                             int n_nodes, int do_relu) {
    __shared__ float Ws[D * D];
    __shared__ float Wm[D * D];
    for (int i = threadIdx.x; i < D * D; i += blockDim.x) {
        Ws[i] = Wself[i];
        Wm[i] = Wmsg[i];
    }
    __syncthreads();
    int lane = threadIdx.x & 63;
    int wave = threadIdx.x >> 6;
    int wpb = blockDim.x >> 6;
    float bj = bias[lane];
    for (int n = blockIdx.x * wpb + wave; n < n_nodes; n += gridDim.x * wpb) {
        float xv = xin[(size_t)n * D + lane];
        float av = agg[(size_t)n * D + lane];
        float acc = bj;
#pragma unroll
        for (int k = 0; k < D; ++k) {
            acc += __shfl(xv, k, 64) * Ws[k * D + lane]
                 + __shfl(av, k, 64) * Wm[k * D + lane];
        }
        if (do_relu) acc = fmaxf(acc, 0.f);
        xout[(size_t)n * D + lane] = acc;
    }
}

// ============================================================================
extern "C" void kernel_launch(void* const* d_in, const int* in_sizes, int n_in,
                              void* d_out, int out_size, void* d_ws, size_t ws_size,
                              hipStream_t stream) {
    const float* x0    = (const float*)d_in[0];
    const int*   ei    = (const int*)d_in[1];
    const float* Wmsg  = (const float*)d_in[2];
    const float* Wself = (const float*)d_in[3];
    const float* bias  = (const float*)d_in[4];
    float* out = (float*)d_out;

    const int N = in_sizes[0] / D;         // 50000
    const int E = in_sizes[1] / 2;         // 800000
    const int n_layers = in_sizes[4] / D;  // 3

    const int* src = ei;
    const int* dst = ei + E;

    const int NB_BLOCKS = (N + 255) / 256;                 // scan blocks (196)
    const size_t NB = (size_t)N * D * sizeof(float);       // 12.8 MB
    const size_t need = NB + (size_t)E * 4 + (size_t)(N + 1) * 4
                      + (size_t)N * 4 + (size_t)N * 4
                      + (size_t)NB_BLOCKS * 4 * 2 + 256;   // ~16.85 MB

    if (ws_size >= need && NB_BLOCKS <= 1024) {
        // ---------------- fast path: CSR + fused gather/dense ----------------
        char* p = (char*)d_ws;
        float* A          = (float*)p;  p += NB;
        int*   sorted_src = (int*)p;    p += (size_t)E * 4;
        int*   row_ptr    = (int*)p;    p += (size_t)(N + 1) * 4;
        int*   cursor     = (int*)p;    p += (size_t)N * 4;
        int*   deg        = (int*)p;    p += (size_t)N * 4;
        int*   bsum       = (int*)p;    p += (size_t)NB_BLOCKS * 4;
        int*   boff       = (int*)p;

        hipMemsetAsync(deg, 0, (size_t)N * 4, stream);
        {
            int threads = 256;
            int work = (E >> 2) + 4;   // int4 body + tail coverage
            hist_kernel<<<(work + threads - 1) / threads, threads, 0, stream>>>(dst, deg, E);
            scan_k1<<<NB_BLOCKS, 256, 0, stream>>>(deg, bsum, N);
            scan_k2<<<1, 1024, 0, stream>>>(bsum, boff, NB_BLOCKS);
            scan_k3<<<NB_BLOCKS, 256, 0, stream>>>(deg, boff, row_ptr, cursor, N);
            perm_kernel<<<(work + threads - 1) / threads, threads, 0, stream>>>(
                src, dst, cursor, sorted_src, E);
        }

        const int WPB = 4;                 // 4 waves / 256-thread block
        const int blocks = 768;            // persistent-ish grid, grid-stride

        // ping-pong so the final layer lands on d_out
        const float* cur = x0;
        for (int layer = 0; layer < n_layers; ++layer) {
            int rem = n_layers - 1 - layer;
            float* tgt = (rem % 2 == 0) ? out : A;
            fused_layer<<<blocks, WPB * 64, 0, stream>>>(
                cur, row_ptr, sorted_src,
                Wself + (size_t)layer * D * D,
                Wmsg  + (size_t)layer * D * D,
                bias  + (size_t)layer * D,
                tgt, N, (layer < n_layers - 1) ? 1 : 0);
            cur = tgt;
        }
    } else {
        // ---------------- fallback: atomic path -------------------------------
        float* agg = (float*)d_ws;
        const int EPB = 256 / 64;
        const int scatter_blocks = (E + EPB - 1) / EPB;
        for (int layer = 0; layer < n_layers; ++layer) {
            hipMemsetAsync(agg, 0, NB, stream);
            const float* xin = (layer == 0) ? x0 : out;
            scatter_kernel<<<scatter_blocks, 256, 0, stream>>>(xin, src, dst, agg, E);
            dense_kernel<<<1024, 256, 0, stream>>>(
                xin, agg,
                Wself + (size_t)layer * D * D,
                Wmsg  + (size_t)layer * D * D,
                bias  + (size_t)layer * D,
                out, N, (layer < n_layers - 1) ? 1 : 0);
        }
    }
}

// Round 4
// 340.502 us; speedup vs baseline: 2.5202x; 1.1440x over previous
//
#include <hip/hip_runtime.h>

#define D 64

__device__ __forceinline__ float bcast(float v, int lane_lit) {
    return __int_as_float(__builtin_amdgcn_readlane(__float_as_int(v), lane_lit));
}

// ================= CSR build (counting sort by dst) =========================
__global__ void hist_kernel(const int* __restrict__ dst, int* __restrict__ deg, int E) {
    int i = blockIdx.x * blockDim.x + threadIdx.x;
    int E4 = E >> 2;
    if (i < E4) {
        int4 d4 = reinterpret_cast<const int4*>(dst)[i];
        atomicAdd(&deg[d4.x], 1);
        atomicAdd(&deg[d4.y], 1);
        atomicAdd(&deg[d4.z], 1);
        atomicAdd(&deg[d4.w], 1);
    }
    if (i < (E & 3)) atomicAdd(&deg[dst[E4 * 4 + i]], 1);
}

__global__ void scan_k1(const int* __restrict__ deg, int* __restrict__ bsum, int n) {
    __shared__ int sh[256];
    int t = threadIdx.x;
    int g = blockIdx.x * 256 + t;
    int v = (g < n) ? deg[g] : 0;
    sh[t] = v;
    __syncthreads();
    for (int off = 1; off < 256; off <<= 1) {
        int u = (t >= off) ? sh[t - off] : 0;
        __syncthreads();
        sh[t] += u;
        __syncthreads();
    }
    if (t == 255) bsum[blockIdx.x] = sh[255];
}

__global__ void scan_k2(const int* __restrict__ bsum, int* __restrict__ boff, int nb) {
    __shared__ int sh[1024];
    int t = threadIdx.x;
    int v = (t < nb) ? bsum[t] : 0;
    sh[t] = v;
    __syncthreads();
    for (int off = 1; off < 1024; off <<= 1) {
        int u = (t >= off) ? sh[t - off] : 0;
        __syncthreads();
        sh[t] += u;
        __syncthreads();
    }
    if (t < nb) boff[t] = sh[t] - v;
}

__global__ void scan_k3(const int* __restrict__ deg, const int* __restrict__ boff,
                        int* __restrict__ row_ptr, int* __restrict__ cursor, int n) {
    __shared__ int sh[256];
    int t = threadIdx.x;
    int g = blockIdx.x * 256 + t;
    int v = (g < n) ? deg[g] : 0;
    sh[t] = v;
    __syncthreads();
    for (int off = 1; off < 256; off <<= 1) {
        int u = (t >= off) ? sh[t - off] : 0;
        __syncthreads();
        sh[t] += u;
        __syncthreads();
    }
    if (g < n) {
        int excl = sh[t] - v + boff[blockIdx.x];
        row_ptr[g] = excl;
        cursor[g] = excl;
        if (g == n - 1) row_ptr[n] = excl + v;
    }
}

__global__ void perm_kernel(const int* __restrict__ src, const int* __restrict__ dst,
                            int* __restrict__ cursor, int* __restrict__ sorted_src, int E) {
    int i = blockIdx.x * blockDim.x + threadIdx.x;
    int E4 = E >> 2;
    if (i < E4) {
        int4 d4 = reinterpret_cast<const int4*>(dst)[i];
        int4 s4 = reinterpret_cast<const int4*>(src)[i];
        int p0 = atomicAdd(&cursor[d4.x], 1);
        int p1 = atomicAdd(&cursor[d4.y], 1);
        int p2 = atomicAdd(&cursor[d4.z], 1);
        int p3 = atomicAdd(&cursor[d4.w], 1);
        sorted_src[p0] = s4.x;
        sorted_src[p1] = s4.y;
        sorted_src[p2] = s4.z;
        sorted_src[p3] = s4.w;
    }
    if (i < (E & 3)) {
        int e = E4 * 4 + i;
        int p = atomicAdd(&cursor[dst[e]], 1);
        sorted_src[p] = src[e];
    }
}

// ================= gather: agg[n] = sum_{e in row n} xin[src_e] =============
// Lean kernel: ~40 VGPR -> 8 waves/SIMD. One wave per node, 16 loads in flight.
__global__ void __launch_bounds__(256)
gather_kernel(const float* __restrict__ xin,
              const int* __restrict__ row_ptr,
              const int* __restrict__ sorted_src,
              float* __restrict__ agg, int n_nodes) {
    int lane = threadIdx.x & 63;
    int n = blockIdx.x * (blockDim.x >> 6) + (threadIdx.x >> 6);
    if (n >= n_nodes) return;

    int beg = row_ptr[n];
    int end = row_ptr[n + 1];

    float a0 = 0.f, a1 = 0.f, a2 = 0.f, a3 = 0.f;
    int e = beg;
    for (; e + 16 <= end; e += 16) {
        int s[16];
#pragma unroll
        for (int i = 0; i < 16; ++i) s[i] = sorted_src[e + i];
        float v[16];
#pragma unroll
        for (int i = 0; i < 16; ++i) v[i] = xin[((unsigned)s[i] << 6) + lane];
        a0 += ((v[0] + v[1]) + (v[2] + v[3]));
        a1 += ((v[4] + v[5]) + (v[6] + v[7]));
        a2 += ((v[8] + v[9]) + (v[10] + v[11]));
        a3 += ((v[12] + v[13]) + (v[14] + v[15]));
    }
    for (; e + 4 <= end; e += 4) {
        int s0 = sorted_src[e + 0], s1 = sorted_src[e + 1];
        int s2 = sorted_src[e + 2], s3 = sorted_src[e + 3];
        a0 += xin[((unsigned)s0 << 6) + lane];
        a1 += xin[((unsigned)s1 << 6) + lane];
        a2 += xin[((unsigned)s2 << 6) + lane];
        a3 += xin[((unsigned)s3 << 6) + lane];
    }
    for (; e < end; ++e) a0 += xin[((unsigned)sorted_src[e] << 6) + lane];

    agg[((unsigned)n << 6) + lane] = (a0 + a1) + (a2 + a3);
}

// ============ dense: out[n] = xin[n]@Ws + agg[n]@Wm + b (+ReLU) =============
// W columns cached in regs (spills to AGPR ok - VALU-bound streaming kernel).
// Row-wise in-place safe: out may alias xin or agg.
__global__ void __launch_bounds__(256)
dense_kernel2(const float* __restrict__ xin,
              const float* __restrict__ agg,
              const float* __restrict__ Wself,
              const float* __restrict__ Wmsg,
              const float* __restrict__ bias,
              float* __restrict__ xout,
              int n_nodes, int do_relu) {
    int lane = threadIdx.x & 63;
    int wave = threadIdx.x >> 6;
    int wpb = blockDim.x >> 6;

    float Wsc[D], Wmc[D];
#pragma unroll
    for (int k = 0; k < D; ++k) {
        Wsc[k] = Wself[k * D + lane];
        Wmc[k] = Wmsg[k * D + lane];
    }
    float bj = bias[lane];

    for (int n = blockIdx.x * wpb + wave; n < n_nodes; n += gridDim.x * wpb) {
        float xv = xin[((unsigned)n << 6) + lane];
        float av = agg[((unsigned)n << 6) + lane];

        float acc0 = bj, acc1 = 0.f, acc2 = 0.f, acc3 = 0.f;
#pragma unroll
        for (int k = 0; k < D; k += 4) {
            acc0 = fmaf(bcast(xv, k + 0), Wsc[k + 0], acc0);
            acc1 = fmaf(bcast(xv, k + 1), Wsc[k + 1], acc1);
            acc2 = fmaf(bcast(xv, k + 2), Wsc[k + 2], acc2);
            acc3 = fmaf(bcast(xv, k + 3), Wsc[k + 3], acc3);
            acc0 = fmaf(bcast(av, k + 0), Wmc[k + 0], acc0);
            acc1 = fmaf(bcast(av, k + 1), Wmc[k + 1], acc1);
            acc2 = fmaf(bcast(av, k + 2), Wmc[k + 2], acc2);
            acc3 = fmaf(bcast(av, k + 3), Wmc[k + 3], acc3);
        }
        float acc = (acc0 + acc1) + (acc2 + acc3);
        if (do_relu) acc = fmaxf(acc, 0.f);
        xout[((unsigned)n << 6) + lane] = acc;
    }
}

// ================= fallback (atomic path) ===================================
__global__ void scatter_kernel(const float* __restrict__ x,
                               const int* __restrict__ src,
                               const int* __restrict__ dst,
                               float* __restrict__ agg, int n_edges) {
    int e = blockIdx.x * (blockDim.x >> 6) + (threadIdx.x >> 6);
    int lane = threadIdx.x & 63;
    if (e >= n_edges) return;
    float v = x[(size_t)src[e] * D + lane];
    unsafeAtomicAdd(&agg[(size_t)dst[e] * D + lane], v);
}

__global__ void dense_kernel(const float* __restrict__ xin,
                             const float* __restrict__ agg,
                             const float* __restrict__ Wself,
                             const float* __restrict__ Wmsg,
                             const float* __restrict__ bias,
                             float* __restrict__ xout,
                             int n_nodes, int do_relu) {
    __shared__ float Ws[D * D];
    __shared__ float Wm[D * D];
    for (int i = threadIdx.x; i < D * D; i += blockDim.x) {
        Ws[i] = Wself[i];
        Wm[i] = Wmsg[i];
    }
    __syncthreads();
    int lane = threadIdx.x & 63;
    int wave = threadIdx.x >> 6;
    int wpb = blockDim.x >> 6;
    float bj = bias[lane];
    for (int n = blockIdx.x * wpb + wave; n < n_nodes; n += gridDim.x * wpb) {
        float xv = xin[(size_t)n * D + lane];
        float av = agg[(size_t)n * D + lane];
        float acc = bj;
#pragma unroll
        for (int k = 0; k < D; ++k) {
            acc += __shfl(xv, k, 64) * Ws[k * D + lane]
                 + __shfl(av, k, 64) * Wm[k * D + lane];
        }
        if (do_relu) acc = fmaxf(acc, 0.f);
        xout[(size_t)n * D + lane] = acc;
    }
}

// ============================================================================
extern "C" void kernel_launch(void* const* d_in, const int* in_sizes, int n_in,
                              void* d_out, int out_size, void* d_ws, size_t ws_size,
                              hipStream_t stream) {
    const float* x0    = (const float*)d_in[0];
    const int*   ei    = (const int*)d_in[1];
    const float* Wmsg  = (const float*)d_in[2];
    const float* Wself = (const float*)d_in[3];
    const float* bias  = (const float*)d_in[4];
    float* out = (float*)d_out;

    const int N = in_sizes[0] / D;         // 50000
    const int E = in_sizes[1] / 2;         // 800000
    const int n_layers = in_sizes[4] / D;  // 3

    const int* src = ei;
    const int* dst = ei + E;

    const int NB_BLOCKS = (N + 255) / 256;
    const size_t NB = (size_t)N * D * sizeof(float);
    const size_t need = NB + (size_t)E * 4 + (size_t)(N + 1) * 4
                      + (size_t)N * 4 + (size_t)N * 4
                      + (size_t)NB_BLOCKS * 4 * 2 + 256;

    if (ws_size >= need && NB_BLOCKS <= 1024) {
        char* p = (char*)d_ws;
        float* A          = (float*)p;  p += NB;
        int*   sorted_src = (int*)p;    p += (size_t)E * 4;
        int*   row_ptr    = (int*)p;    p += (size_t)(N + 1) * 4;
        int*   cursor     = (int*)p;    p += (size_t)N * 4;
        int*   deg        = (int*)p;    p += (size_t)N * 4;
        int*   bsum       = (int*)p;    p += (size_t)NB_BLOCKS * 4;
        int*   boff       = (int*)p;

        hipMemsetAsync(deg, 0, (size_t)N * 4, stream);
        {
            int threads = 256;
            int work = (E >> 2) + 4;
            hist_kernel<<<(work + threads - 1) / threads, threads, 0, stream>>>(dst, deg, E);
            scan_k1<<<NB_BLOCKS, 256, 0, stream>>>(deg, bsum, N);
            scan_k2<<<1, 1024, 0, stream>>>(bsum, boff, NB_BLOCKS);
            scan_k3<<<NB_BLOCKS, 256, 0, stream>>>(deg, boff, row_ptr, cursor, N);
            perm_kernel<<<(work + threads - 1) / threads, threads, 0, stream>>>(
                src, dst, cursor, sorted_src, E);
        }

        const int WPB = 4;
        const int gather_blocks = (N + WPB - 1) / WPB;   // one wave per node
        const int dense_blocks = 1024;                   // grid-stride, W amortized

        // Buffer choreography (one ws buffer A + d_out as ping):
        //   gather(cur -> aggbuf); dense(cur, aggbuf -> tgt)
        //   aggbuf alternates A, out, A...; tgt = aggbuf except last layer -> out.
        //   All in-place cases are row-wise safe.
        const float* cur = x0;
        for (int layer = 0; layer < n_layers; ++layer) {
            float* aggbuf = (layer % 2 == 0) ? A : out;
            float* tgt = (layer == n_layers - 1) ? out : aggbuf;
            gather_kernel<<<gather_blocks, WPB * 64, 0, stream>>>(
                cur, row_ptr, sorted_src, aggbuf, N);
            dense_kernel2<<<dense_blocks, 256, 0, stream>>>(
                cur, aggbuf,
                Wself + (size_t)layer * D * D,
                Wmsg  + (size_t)layer * D * D,
                bias  + (size_t)layer * D,
                tgt, N, (layer < n_layers - 1) ? 1 : 0);
            cur = tgt;
        }
    } else {
        float* agg = (float*)d_ws;
        const int EPB = 256 / 64;
        const int scatter_blocks = (E + EPB - 1) / EPB;
        for (int layer = 0; layer < n_layers; ++layer) {
            hipMemsetAsync(agg, 0, NB, stream);
            const float* xin = (layer == 0) ? x0 : out;
            scatter_kernel<<<scatter_blocks, 256, 0, stream>>>(xin, src, dst, agg, E);
            dense_kernel<<<1024, 256, 0, stream>>>(
                xin, agg,
                Wself + (size_t)layer * D * D,
                Wmsg  + (size_t)layer * D * D,
                bias  + (size_t)layer * D,
                out, N, (layer < n_layers - 1) ? 1 : 0);
        }
    }
}